// Round 1
// baseline (1448.348 us; speedup 1.0000x reference)
//
#include <hip/hip_runtime.h>
#include <hip/hip_bf16.h>
#include <math.h>

#define HW 16384
#define Wd 128

// ---------------------------------------------------------------------------
// FFT amplitude-replacement kernel: one block per (tensor, b, c) plane.
// Full complex 2D 128x128 FFT in LDS; forward, amp*exp(i*angle), inverse.
// ---------------------------------------------------------------------------
__device__ __forceinline__ void fft_dim(float* re, float* im,
                                        const float* twc, const float* tws,
                                        int tid, int cols)
{
  // bit-reverse permutation along the transform dimension
  for (int idx = tid; idx < 16384; idx += 256) {
    int f = idx & 127, g = idx >> 7;
    int r = cols ? f : g;   // transform id (fast across lanes for cols)
    int i = cols ? g : f;   // element index (fast across lanes for rows)
    int j = (int)(__brev((unsigned)i) >> 25);
    if (i < j) {
      int e0 = cols ? (i * 128 + r) : (r * 128 + i);
      int e1 = cols ? (j * 128 + r) : (r * 128 + j);
      float t0 = re[e0]; re[e0] = re[e1]; re[e1] = t0;
      float t1 = im[e0]; im[e0] = im[e1]; im[e1] = t1;
    }
  }
  __syncthreads();
  for (int s = 0; s < 7; ++s) {
    int half = 1 << s;
    for (int idx = tid; idx < 8192; idx += 256) {
      int t, r;
      if (cols) { r = idx & 127; t = idx >> 7; }
      else      { r = idx >> 6;  t = idx & 63; }
      int pos = t & (half - 1);
      int i0 = ((t >> s) << (s + 1)) + pos;
      int i1 = i0 + half;
      int e0 = cols ? (i0 * 128 + r) : (r * 128 + i0);
      int e1 = cols ? (i1 * 128 + r) : (r * 128 + i1);
      int tj = pos << (6 - s);
      float cs = twc[tj], sn = tws[tj];
      float br = re[e1], bi = im[e1];
      float tr = br * cs - bi * sn;
      float ti = br * sn + bi * cs;
      float ar = re[e0], ai = im[e0];
      re[e0] = ar + tr; im[e0] = ai + ti;
      re[e1] = ar - tr; im[e1] = ai - ti;
    }
    __syncthreads();
  }
}

__global__ __launch_bounds__(256) void fft_amp_kernel(
    const float* __restrict__ x, const float* __restrict__ xref,
    const float* __restrict__ amp, float* __restrict__ feat)
{
  __shared__ float sre[16384];
  __shared__ float sim[16384];
  __shared__ float twc[64];
  __shared__ float tws[64];
  int tid = threadIdx.x;
  int blk = blockIdx.x;          // 0..255
  int tensor = blk >> 7;         // 0 = x, 1 = x_ref
  int plane = blk & 127;         // b*64 + c
  const float* src = (tensor ? xref : x) + (size_t)plane * HW;
  if (tid < 64) {
    float ang = -6.283185307179586f * (float)tid / 128.f;
    float sn, cs;
    __sincosf(ang, &sn, &cs);
    twc[tid] = cs; tws[tid] = sn;
  }
  for (int i = tid; i < 16384; i += 256) { sre[i] = src[i]; sim[i] = 0.f; }
  __syncthreads();
  // forward 2D FFT
  fft_dim(sre, sim, twc, tws, tid, 0);
  fft_dim(sre, sim, twc, tws, tid, 1);
  // amplitude replacement + conjugate (prep for inverse-via-forward)
  const float* ampb = amp + (size_t)plane * (128 * 65);
  for (int idx = tid; idx < 16384; idx += 256) {
    int ky = idx >> 7, kx = idx & 127;
    float A = (kx <= 64) ? ampb[ky * 65 + kx]
                         : ampb[((128 - ky) & 127) * 65 + (128 - kx)];
    float th = atan2f(sim[idx], sre[idx]);
    float sn, cs;
    __sincosf(th, &sn, &cs);
    sre[idx] = A * cs;
    sim[idx] = -A * sn;   // conj
  }
  __syncthreads();
  // inverse = conj(fft(conj(Y)))/N ; we only need the real part
  fft_dim(sre, sim, twc, tws, tid, 0);
  fft_dim(sre, sim, twc, tws, tid, 1);
  int b = plane >> 6, c = plane & 63;
  float* dst = feat + ((size_t)b * 128 + tensor * 64 + c) * HW;
  for (int i = tid; i < 16384; i += 256) dst[i] = sre[i] * (1.f / 16384.f);
}

// ---------------------------------------------------------------------------
// Generic 3x3 conv, pad=1, H=W=128. Optional channel-concat via (in1,in2).
// Block: (b, co, 8-row strip). 256 threads: 128 cols x 2 row-groups,
// each thread 4 consecutive output rows (6 input rows staged in registers).
// ---------------------------------------------------------------------------
__global__ __launch_bounds__(256) void conv3x3_kernel(
    const float* __restrict__ in1, const float* __restrict__ in2, int csplit,
    const float* __restrict__ w, const float* __restrict__ bias,
    float* __restrict__ out, int Cin, int Cout, int lrelu)
{
  __shared__ float wl[1152];        // up to 128 ci * 9
  __shared__ float tile[10][132];   // rows y0-1..y0+8, cols -1..128
  int blk = blockIdx.x;
  int ystrip = blk & 15;
  int co = (blk >> 4) % Cout;
  int b = blk / (Cout << 4);
  int tid = threadIdx.x;
  int col = tid & 127;
  int rg = tid >> 7;                // 0..1
  int y0 = ystrip << 3;
  for (int i = tid; i < Cin * 9; i += 256) wl[i] = w[co * Cin * 9 + i];
  float acc[4] = {0.f, 0.f, 0.f, 0.f};
  int tr = rg << 2;                 // tile-row base for this thread
  for (int ci = 0; ci < Cin; ++ci) {
    const float* src = (ci < csplit)
        ? in1 + ((size_t)b * csplit + ci) * HW
        : in2 + ((size_t)b * (Cin - csplit) + (ci - csplit)) * HW;
    __syncthreads();
    for (int idx = tid; idx < 1300; idx += 256) {
      int r = idx / 130;
      int cc = idx - r * 130 - 1;   // -1..128
      int y = y0 - 1 + r;
      float v = 0.f;
      if ((unsigned)y < 128u && (unsigned)cc < 128u) v = src[y * Wd + cc];
      tile[r][cc + 1] = v;
    }
    __syncthreads();
    float wr[9];
    #pragma unroll
    for (int t = 0; t < 9; ++t) wr[t] = wl[ci * 9 + t];
    float tv[6][3];
    #pragma unroll
    for (int rr = 0; rr < 6; ++rr) {
      #pragma unroll
      for (int vv = 0; vv < 3; ++vv)
        tv[rr][vv] = tile[tr + rr][col + vv];
    }
    #pragma unroll
    for (int j = 0; j < 4; ++j) {
      float s = 0.f;
      #pragma unroll
      for (int u = 0; u < 3; ++u) {
        #pragma unroll
        for (int vv = 0; vv < 3; ++vv)
          s += tv[j + u][vv] * wr[u * 3 + vv];
      }
      acc[j] += s;
    }
  }
  float bv = bias[co];
  size_t ob = ((size_t)b * Cout + co) * HW;
  int rowbase = y0 + (rg << 2);
  #pragma unroll
  for (int j = 0; j < 4; ++j) {
    float v = acc[j] + bv;
    if (lrelu) v = v >= 0.f ? v : 0.1f * v;
    out[ob + (size_t)(rowbase + j) * Wd + col] = v;
  }
}

// ---------------------------------------------------------------------------
// Deformable conv (fused sampling + GEMM). Block: (b, 16-pixel row chunk).
// dy(k)=om[2k], dx(k)=om[2k+1], mask(k)=sigmoid(om[18+k]).
// ---------------------------------------------------------------------------
__global__ __launch_bounds__(256) void deform_kernel(
    const float* __restrict__ x, const float* __restrict__ om,
    const float* __restrict__ wd, const float* __restrict__ bias,
    float* __restrict__ out)
{
  __shared__ float S[576][16];      // [k*64+c][p], mask applied
  __shared__ int   gy0[144];
  __shared__ int   gx0[144];
  __shared__ float gwy[144];
  __shared__ float gwx[144];
  __shared__ float gm[144];
  int blk = blockIdx.x;
  int b = blk >> 10;
  int pb = (blk & 1023) << 4;       // pixel base (16 pixels, same row)
  int y = pb >> 7;
  int xbcol = pb & 127;
  int tid = threadIdx.x;
  if (tid < 144) {
    int k = tid >> 4, p = tid & 15;
    int xx = xbcol + p;
    const float* omb = om + (size_t)b * 27 * HW + (size_t)y * Wd + xx;
    float dy = omb[(2 * k) * HW];
    float dx = omb[(2 * k + 1) * HW];
    float mv = omb[(18 + k) * HW];
    mv = 1.f / (1.f + __expf(-mv));
    float py = (float)(y + (k / 3) - 1) + dy;
    float px = (float)(xx + (k % 3) - 1) + dx;
    float fy = floorf(py), fx = floorf(px);
    gy0[tid] = (int)fy; gx0[tid] = (int)fx;
    gwy[tid] = py - fy; gwx[tid] = px - fx;
    gm[tid] = mv;
  }
  __syncthreads();
  {
    int c = tid & 63, q = tid >> 6;
    const float* xb = x + ((size_t)b * 64 + c) * HW;
    for (int k = 0; k < 9; ++k) {
      #pragma unroll
      for (int i = 0; i < 4; ++i) {
        int p = q * 4 + i;
        int gi = k * 16 + p;
        int yy = gy0[gi], xc = gx0[gi];
        float wy = gwy[gi], wx = gwx[gi];
        float v00 = 0.f, v01 = 0.f, v10 = 0.f, v11 = 0.f;
        if ((unsigned)yy < 128u) {
          if ((unsigned)xc < 128u)       v00 = xb[yy * Wd + xc];
          if ((unsigned)(xc + 1) < 128u) v01 = xb[yy * Wd + xc + 1];
        }
        if ((unsigned)(yy + 1) < 128u) {
          if ((unsigned)xc < 128u)       v10 = xb[(yy + 1) * Wd + xc];
          if ((unsigned)(xc + 1) < 128u) v11 = xb[(yy + 1) * Wd + xc + 1];
        }
        float vs = (v00 * (1.f - wx) + v01 * wx) * (1.f - wy)
                 + (v10 * (1.f - wx) + v11 * wx) * wy;
        S[k * 64 + c][p] = vs * gm[gi];
      }
    }
  }
  __syncthreads();
  {
    int co = tid >> 2, g = tid & 3;
    float4 acc = make_float4(0.f, 0.f, 0.f, 0.f);
    const float* wco = wd + (size_t)co * 576;   // w[co][c][k]
    for (int ci = 0; ci < 64; ++ci) {
      #pragma unroll
      for (int k = 0; k < 9; ++k) {
        float wv = wco[ci * 9 + k];
        const float4 sv = *reinterpret_cast<const float4*>(&S[k * 64 + ci][g * 4]);
        acc.x += wv * sv.x; acc.y += wv * sv.y;
        acc.z += wv * sv.z; acc.w += wv * sv.w;
      }
    }
    float bv = bias[co];
    float r[4] = {acc.x + bv, acc.y + bv, acc.z + bv, acc.w + bv};
    float* ob = out + ((size_t)b * 64 + co) * HW + pb + g * 4;
    #pragma unroll
    for (int i = 0; i < 4; ++i) {
      float v = r[i];
      ob[i] = v >= 0.f ? v : 0.1f * v;
    }
  }
}

// ---------------------------------------------------------------------------
// 1x1 conv, Cin=Cout=64, with leaky-relu.
// ---------------------------------------------------------------------------
__global__ __launch_bounds__(256) void conv1x1_kernel(
    const float* __restrict__ in, const float* __restrict__ w,
    const float* __restrict__ bias, float* __restrict__ out)
{
  int t = blockIdx.x * 256 + threadIdx.x;   // B*64*HW = 2^21 threads
  int pix = t & (HW - 1);
  int co = (t >> 14) & 63;
  int b = t >> 20;
  const float* ib = in + ((size_t)b << 20) + pix;
  float acc = bias[co];
  #pragma unroll 8
  for (int ci = 0; ci < 64; ++ci)
    acc += w[(co << 6) + ci] * ib[ci << 14];
  out[t] = acc >= 0.f ? acc : 0.1f * acc;
}

// ---------------------------------------------------------------------------
extern "C" void kernel_launch(void* const* d_in, const int* in_sizes, int n_in,
                              void* d_out, int out_size, void* d_ws, size_t ws_size,
                              hipStream_t stream) {
  (void)in_sizes; (void)n_in; (void)out_size; (void)ws_size;
  const float* x       = (const float*)d_in[0];
  const float* x_ref   = (const float*)d_in[1];
  const float* amp     = (const float*)d_in[2];
  const float* new_inp = (const float*)d_in[3];
  const float* w_off1  = (const float*)d_in[4];
  const float* b_off1  = (const float*)d_in[5];
  const float* w_off2  = (const float*)d_in[6];
  const float* b_off2  = (const float*)d_in[7];
  const float* w_om    = (const float*)d_in[8];
  const float* b_om    = (const float*)d_in[9];
  const float* w_dcn   = (const float*)d_in[10];
  const float* b_dcn   = (const float*)d_in[11];
  const float* w_1x1   = (const float*)d_in[12];
  const float* b_1x1   = (const float*)d_in[13];
  const float* w_3x3   = (const float*)d_in[14];
  const float* b_3x3   = (const float*)d_in[15];
  float* out = (float*)d_out;

  float* ws    = (float*)d_ws;
  float* feat  = ws;                    // B*128*HW = 4,194,304 f
  float* buf1  = feat + 4194304;        // B*64*HW  = 2,097,152 f
  float* buf2  = buf1 + 2097152;        // B*64*HW
  float* ombuf = buf2 + 2097152;        // B*27*HW  =   884,736 f

  // 1) FFT amplitude swap -> feat = concat([x_new, ref_new], axis=1)
  hipLaunchKernelGGL(fft_amp_kernel, dim3(256), dim3(256), 0, stream,
                     x, x_ref, amp, feat);
  // 2) conv1 (128->64) + lrelu
  hipLaunchKernelGGL(conv3x3_kernel, dim3(2048), dim3(256), 0, stream,
                     feat, (const float*)nullptr, 128, w_off1, b_off1, buf1, 128, 64, 1);
  // 3) conv2 (64->64) + lrelu
  hipLaunchKernelGGL(conv3x3_kernel, dim3(2048), dim3(256), 0, stream,
                     buf1, (const float*)nullptr, 64, w_off2, b_off2, buf2, 64, 64, 1);
  // 4) om conv (64->27), no activation
  hipLaunchKernelGGL(conv3x3_kernel, dim3(864), dim3(256), 0, stream,
                     buf2, (const float*)nullptr, 64, w_om, b_om, ombuf, 64, 27, 0);
  // 5) deformable conv (x, om) -> buf1, + bias + lrelu
  hipLaunchKernelGGL(deform_kernel, dim3(2048), dim3(256), 0, stream,
                     x, ombuf, w_dcn, b_dcn, buf1);
  // 6) 1x1 conv + lrelu -> buf2
  hipLaunchKernelGGL(conv1x1_kernel, dim3(8192), dim3(256), 0, stream,
                     buf1, w_1x1, b_1x1, buf2);
  // 7) final 3x3 conv on concat([d2, new_inp]) -> out (no activation)
  hipLaunchKernelGGL(conv3x3_kernel, dim3(2048), dim3(256), 0, stream,
                     buf2, new_inp, 64, w_3x3, b_3x3, out, 128, 64, 0);
}

// Round 2
// 946.338 us; speedup vs baseline: 1.5305x; 1.5305x over previous
//
#include <hip/hip_runtime.h>
#include <hip/hip_bf16.h>
#include <math.h>

#define HW 16384
#define Wd 128

// ---------------------------------------------------------------------------
// FFT amplitude-replacement kernel: one block per (tensor, b, c) plane.
// Full complex 2D 128x128 FFT in LDS; forward, amp*exp(i*angle), inverse.
// ---------------------------------------------------------------------------
__device__ __forceinline__ void fft_dim(float* re, float* im,
                                        const float* twc, const float* tws,
                                        int tid, int cols)
{
  // bit-reverse permutation along the transform dimension
  for (int idx = tid; idx < 16384; idx += 256) {
    int f = idx & 127, g = idx >> 7;
    int r = cols ? f : g;   // transform id (fast across lanes for cols)
    int i = cols ? g : f;   // element index (fast across lanes for rows)
    int j = (int)(__brev((unsigned)i) >> 25);
    if (i < j) {
      int e0 = cols ? (i * 128 + r) : (r * 128 + i);
      int e1 = cols ? (j * 128 + r) : (r * 128 + j);
      float t0 = re[e0]; re[e0] = re[e1]; re[e1] = t0;
      float t1 = im[e0]; im[e0] = im[e1]; im[e1] = t1;
    }
  }
  __syncthreads();
  for (int s = 0; s < 7; ++s) {
    int half = 1 << s;
    for (int idx = tid; idx < 8192; idx += 256) {
      int t, r;
      if (cols) { r = idx & 127; t = idx >> 7; }
      else      { r = idx >> 6;  t = idx & 63; }
      int pos = t & (half - 1);
      int i0 = ((t >> s) << (s + 1)) + pos;
      int i1 = i0 + half;
      int e0 = cols ? (i0 * 128 + r) : (r * 128 + i0);
      int e1 = cols ? (i1 * 128 + r) : (r * 128 + i1);
      int tj = pos << (6 - s);
      float cs = twc[tj], sn = tws[tj];
      float br = re[e1], bi = im[e1];
      float tr = br * cs - bi * sn;
      float ti = br * sn + bi * cs;
      float ar = re[e0], ai = im[e0];
      re[e0] = ar + tr; im[e0] = ai + ti;
      re[e1] = ar - tr; im[e1] = ai - ti;
    }
    __syncthreads();
  }
}

__global__ __launch_bounds__(256) void fft_amp_kernel(
    const float* __restrict__ x, const float* __restrict__ xref,
    const float* __restrict__ amp, float* __restrict__ feat)
{
  __shared__ float sre[16384];
  __shared__ float sim[16384];
  __shared__ float twc[64];
  __shared__ float tws[64];
  int tid = threadIdx.x;
  int blk = blockIdx.x;          // 0..255
  int tensor = blk >> 7;         // 0 = x, 1 = x_ref
  int plane = blk & 127;         // b*64 + c
  const float* src = (tensor ? xref : x) + (size_t)plane * HW;
  if (tid < 64) {
    float ang = -6.283185307179586f * (float)tid / 128.f;
    float sn, cs;
    __sincosf(ang, &sn, &cs);
    twc[tid] = cs; tws[tid] = sn;
  }
  for (int i = tid; i < 16384; i += 256) { sre[i] = src[i]; sim[i] = 0.f; }
  __syncthreads();
  // forward 2D FFT
  fft_dim(sre, sim, twc, tws, tid, 0);
  fft_dim(sre, sim, twc, tws, tid, 1);
  // amplitude replacement + conjugate (prep for inverse-via-forward)
  const float* ampb = amp + (size_t)plane * (128 * 65);
  for (int idx = tid; idx < 16384; idx += 256) {
    int ky = idx >> 7, kx = idx & 127;
    float A = (kx <= 64) ? ampb[ky * 65 + kx]
                         : ampb[((128 - ky) & 127) * 65 + (128 - kx)];
    float th = atan2f(sim[idx], sre[idx]);
    float sn, cs;
    __sincosf(th, &sn, &cs);
    sre[idx] = A * cs;
    sim[idx] = -A * sn;   // conj
  }
  __syncthreads();
  // inverse = conj(fft(conj(Y)))/N ; we only need the real part
  fft_dim(sre, sim, twc, tws, tid, 0);
  fft_dim(sre, sim, twc, tws, tid, 1);
  int b = plane >> 6, c = plane & 63;
  float* dst = feat + ((size_t)b * 128 + tensor * 64 + c) * HW;
  for (int i = tid; i < 16384; i += 256) dst[i] = sre[i] * (1.f / 16384.f);
}

// ---------------------------------------------------------------------------
// 3x3 conv v2, pad=1, H=W=128. 8 output channels per block, 2 rows/thread.
// Grid: B * cogroups * 32 strips. 256 threads = 128 cols x 2 row-groups.
// Double-buffered LDS tile (one barrier/ci), scalar-uniform weight loads,
// division-free float4 staging. Optional channel concat via (in1,in2,csplit).
// ---------------------------------------------------------------------------
#define COG 8
__global__ __launch_bounds__(256) void conv3x3_v2(
    const float* __restrict__ in1, const float* __restrict__ in2, int csplit,
    const float* __restrict__ w, const float* __restrict__ bias,
    float* __restrict__ out, int Cin, int Cout, int cogroups, int lrelu)
{
  __shared__ float tile[2][6][136];   // rows y0-1..y0+4, cols: 3=left halo,
                                      // 4..131 interior, 132 right halo
  int blk = blockIdx.x;
  int ystrip = blk & 31;
  int t2 = blk >> 5;
  int cog = t2 % cogroups;
  int b = t2 / cogroups;
  int cobase = cog * COG;
  int tid = threadIdx.x;
  int col = tid & 127;
  int rg = tid >> 7;                  // 0..1
  int y0 = ystrip << 2;               // 4 output rows per block

  // constant zero halos (image is exactly 128 wide -> pad cols always 0)
  if (tid < 24) {
    int bf = tid >> 3 >> 1;           // wrong-cheap decode avoided below
  }
  if (tid < 12) {
    int row = tid >> 1, side = tid & 1;
    tile[0][row][side ? 132 : 3] = 0.f;
    tile[1][row][side ? 132 : 3] = 0.f;
  }

  float acc[COG][2];
  #pragma unroll
  for (int g = 0; g < COG; ++g) { acc[g][0] = 0.f; acc[g][1] = 0.f; }

  // stage ci=0
  {
    const float* src = (0 < csplit) ? in1 + ((size_t)b * csplit) * HW
                                    : in2;
    if (tid < 192) {
      int row = tid >> 5, c4 = (tid & 31) << 2;
      int y = y0 - 1 + row;
      float4 v = make_float4(0.f, 0.f, 0.f, 0.f);
      if ((unsigned)y < 128u)
        v = *reinterpret_cast<const float4*>(src + y * Wd + c4);
      *reinterpret_cast<float4*>(&tile[0][row][4 + c4]) = v;
    }
  }

  for (int ci = 0; ci < Cin; ++ci) {
    // uniform (scalar) weight loads for this ci
    float wv[COG][9];
    #pragma unroll
    for (int g = 0; g < COG; ++g) {
      int co = cobase + g;
      int cc = co < Cout ? co : Cout - 1;
      const float* wp = w + ((size_t)cc * Cin + ci) * 9;
      #pragma unroll
      for (int t = 0; t < 9; ++t) wv[g][t] = wp[t];
    }
    __syncthreads();
    // prefetch next ci into the other buffer
    if (ci + 1 < Cin) {
      int cn = ci + 1;
      const float* src = (cn < csplit)
          ? in1 + ((size_t)b * csplit + cn) * HW
          : in2 + ((size_t)b * (Cin - csplit) + (cn - csplit)) * HW;
      if (tid < 192) {
        int row = tid >> 5, c4 = (tid & 31) << 2;
        int y = y0 - 1 + row;
        float4 v = make_float4(0.f, 0.f, 0.f, 0.f);
        if ((unsigned)y < 128u)
          v = *reinterpret_cast<const float4*>(src + y * Wd + c4);
        *reinterpret_cast<float4*>(&tile[(ci + 1) & 1][row][4 + c4]) = v;
      }
    }
    // compute from current buffer
    const float (*tb)[136] = tile[ci & 1];
    float tv[4][3];
    int tr = rg << 1;
    #pragma unroll
    for (int rr = 0; rr < 4; ++rr) {
      #pragma unroll
      for (int vv = 0; vv < 3; ++vv)
        tv[rr][vv] = tb[tr + rr][col + 3 + vv];
    }
    #pragma unroll
    for (int g = 0; g < COG; ++g) {
      #pragma unroll
      for (int j = 0; j < 2; ++j) {
        float s = 0.f;
        #pragma unroll
        for (int u = 0; u < 3; ++u) {
          #pragma unroll
          for (int vv = 0; vv < 3; ++vv)
            s += tv[j + u][vv] * wv[g][u * 3 + vv];
        }
        acc[g][j] += s;
      }
    }
  }

  // epilogue
  #pragma unroll
  for (int g = 0; g < COG; ++g) {
    int co = cobase + g;
    if (co < Cout) {
      float bv = bias[co];
      size_t ob = ((size_t)b * Cout + co) * HW;
      #pragma unroll
      for (int j = 0; j < 2; ++j) {
        int y = y0 + (rg << 1) + j;
        float v = acc[g][j] + bv;
        if (lrelu) v = v >= 0.f ? v : 0.1f * v;
        out[ob + (size_t)y * Wd + col] = v;
      }
    }
  }
}

// ---------------------------------------------------------------------------
// Deformable conv (fused sampling + GEMM). Block: (b, 16-pixel row chunk).
// dy(k)=om[2k], dx(k)=om[2k+1], mask(k)=sigmoid(om[18+k]).
// ---------------------------------------------------------------------------
__global__ __launch_bounds__(256) void deform_kernel(
    const float* __restrict__ x, const float* __restrict__ om,
    const float* __restrict__ wd, const float* __restrict__ bias,
    float* __restrict__ out)
{
  __shared__ float S[576][16];      // [k*64+c][p], mask applied
  __shared__ int   gy0[144];
  __shared__ int   gx0[144];
  __shared__ float gwy[144];
  __shared__ float gwx[144];
  __shared__ float gm[144];
  int blk = blockIdx.x;
  int b = blk >> 10;
  int pb = (blk & 1023) << 4;       // pixel base (16 pixels, same row)
  int y = pb >> 7;
  int xbcol = pb & 127;
  int tid = threadIdx.x;
  if (tid < 144) {
    int k = tid >> 4, p = tid & 15;
    int xx = xbcol + p;
    const float* omb = om + (size_t)b * 27 * HW + (size_t)y * Wd + xx;
    float dy = omb[(2 * k) * HW];
    float dx = omb[(2 * k + 1) * HW];
    float mv = omb[(18 + k) * HW];
    mv = 1.f / (1.f + __expf(-mv));
    float py = (float)(y + (k / 3) - 1) + dy;
    float px = (float)(xx + (k % 3) - 1) + dx;
    float fy = floorf(py), fx = floorf(px);
    gy0[tid] = (int)fy; gx0[tid] = (int)fx;
    gwy[tid] = py - fy; gwx[tid] = px - fx;
    gm[tid] = mv;
  }
  __syncthreads();
  {
    int c = tid & 63, q = tid >> 6;
    const float* xb = x + ((size_t)b * 64 + c) * HW;
    for (int k = 0; k < 9; ++k) {
      #pragma unroll
      for (int i = 0; i < 4; ++i) {
        int p = q * 4 + i;
        int gi = k * 16 + p;
        int yy = gy0[gi], xc = gx0[gi];
        float wy = gwy[gi], wx = gwx[gi];
        float v00 = 0.f, v01 = 0.f, v10 = 0.f, v11 = 0.f;
        if ((unsigned)yy < 128u) {
          if ((unsigned)xc < 128u)       v00 = xb[yy * Wd + xc];
          if ((unsigned)(xc + 1) < 128u) v01 = xb[yy * Wd + xc + 1];
        }
        if ((unsigned)(yy + 1) < 128u) {
          if ((unsigned)xc < 128u)       v10 = xb[(yy + 1) * Wd + xc];
          if ((unsigned)(xc + 1) < 128u) v11 = xb[(yy + 1) * Wd + xc + 1];
        }
        float vs = (v00 * (1.f - wx) + v01 * wx) * (1.f - wy)
                 + (v10 * (1.f - wx) + v11 * wx) * wy;
        S[k * 64 + c][p] = vs * gm[gi];
      }
    }
  }
  __syncthreads();
  {
    int co = tid >> 2, g = tid & 3;
    float4 acc = make_float4(0.f, 0.f, 0.f, 0.f);
    const float* wco = wd + (size_t)co * 576;   // w[co][c][k]
    for (int ci = 0; ci < 64; ++ci) {
      #pragma unroll
      for (int k = 0; k < 9; ++k) {
        float wv = wco[ci * 9 + k];
        const float4 sv = *reinterpret_cast<const float4*>(&S[k * 64 + ci][g * 4]);
        acc.x += wv * sv.x; acc.y += wv * sv.y;
        acc.z += wv * sv.z; acc.w += wv * sv.w;
      }
    }
    float bv = bias[co];
    float r[4] = {acc.x + bv, acc.y + bv, acc.z + bv, acc.w + bv};
    float* ob = out + ((size_t)b * 64 + co) * HW + pb + g * 4;
    #pragma unroll
    for (int i = 0; i < 4; ++i) {
      float v = r[i];
      ob[i] = v >= 0.f ? v : 0.1f * v;
    }
  }
}

// ---------------------------------------------------------------------------
// 1x1 conv, Cin=Cout=64, with leaky-relu.
// ---------------------------------------------------------------------------
__global__ __launch_bounds__(256) void conv1x1_kernel(
    const float* __restrict__ in, const float* __restrict__ w,
    const float* __restrict__ bias, float* __restrict__ out)
{
  int t = blockIdx.x * 256 + threadIdx.x;   // B*64*HW = 2^21 threads
  int pix = t & (HW - 1);
  int co = (t >> 14) & 63;
  int b = t >> 20;
  const float* ib = in + ((size_t)b << 20) + pix;
  float acc = bias[co];
  #pragma unroll 8
  for (int ci = 0; ci < 64; ++ci)
    acc += w[(co << 6) + ci] * ib[ci << 14];
  out[t] = acc >= 0.f ? acc : 0.1f * acc;
}

// ---------------------------------------------------------------------------
extern "C" void kernel_launch(void* const* d_in, const int* in_sizes, int n_in,
                              void* d_out, int out_size, void* d_ws, size_t ws_size,
                              hipStream_t stream) {
  (void)in_sizes; (void)n_in; (void)out_size; (void)ws_size;
  const float* x       = (const float*)d_in[0];
  const float* x_ref   = (const float*)d_in[1];
  const float* amp     = (const float*)d_in[2];
  const float* new_inp = (const float*)d_in[3];
  const float* w_off1  = (const float*)d_in[4];
  const float* b_off1  = (const float*)d_in[5];
  const float* w_off2  = (const float*)d_in[6];
  const float* b_off2  = (const float*)d_in[7];
  const float* w_om    = (const float*)d_in[8];
  const float* b_om    = (const float*)d_in[9];
  const float* w_dcn   = (const float*)d_in[10];
  const float* b_dcn   = (const float*)d_in[11];
  const float* w_1x1   = (const float*)d_in[12];
  const float* b_1x1   = (const float*)d_in[13];
  const float* w_3x3   = (const float*)d_in[14];
  const float* b_3x3   = (const float*)d_in[15];
  float* out = (float*)d_out;

  float* ws    = (float*)d_ws;
  float* feat  = ws;                    // B*128*HW = 4,194,304 f
  float* buf1  = feat + 4194304;        // B*64*HW  = 2,097,152 f
  float* buf2  = buf1 + 2097152;        // B*64*HW
  float* ombuf = buf2 + 2097152;        // B*27*HW  =   884,736 f

  // 1) FFT amplitude swap -> feat = concat([x_new, ref_new], axis=1)
  hipLaunchKernelGGL(fft_amp_kernel, dim3(256), dim3(256), 0, stream,
                     x, x_ref, amp, feat);
  // 2) conv1 (128->64) + lrelu : cogroups=8 -> grid 2*8*32=512
  hipLaunchKernelGGL(conv3x3_v2, dim3(512), dim3(256), 0, stream,
                     feat, (const float*)nullptr, 128, w_off1, b_off1, buf1,
                     128, 64, 8, 1);
  // 3) conv2 (64->64) + lrelu
  hipLaunchKernelGGL(conv3x3_v2, dim3(512), dim3(256), 0, stream,
                     buf1, (const float*)nullptr, 64, w_off2, b_off2, buf2,
                     64, 64, 8, 1);
  // 4) om conv (64->27), no activation : cogroups=4 -> grid 2*4*32=256
  hipLaunchKernelGGL(conv3x3_v2, dim3(256), dim3(256), 0, stream,
                     buf2, (const float*)nullptr, 64, w_om, b_om, ombuf,
                     64, 27, 4, 0);
  // 5) deformable conv (x, om) -> buf1, + bias + lrelu
  hipLaunchKernelGGL(deform_kernel, dim3(2048), dim3(256), 0, stream,
                     x, ombuf, w_dcn, b_dcn, buf1);
  // 6) 1x1 conv + lrelu -> buf2
  hipLaunchKernelGGL(conv1x1_kernel, dim3(8192), dim3(256), 0, stream,
                     buf1, w_1x1, b_1x1, buf2);
  // 7) final 3x3 conv on concat([d2, new_inp]) -> out (no activation)
  hipLaunchKernelGGL(conv3x3_v2, dim3(512), dim3(256), 0, stream,
                     buf2, new_inp, 64, w_3x3, b_3x3, out, 128, 64, 8, 0);
}

// Round 4
// 765.158 us; speedup vs baseline: 1.8929x; 1.2368x over previous
//
#include <hip/hip_runtime.h>
#include <hip/hip_bf16.h>
#include <math.h>

#define HW 16384
#define Wd 128
#define NT_FFT 1024

// ---------------------------------------------------------------------------
// FFT amplitude-replacement kernel: one block per (tensor, b, c) plane.
// Full complex 2D 128x128 FFT in LDS; forward, amp*exp(i*angle), inverse.
// 1024 threads (16 waves) to hide LDS latency; 1 block/CU (128KB LDS).
// ---------------------------------------------------------------------------
__device__ __forceinline__ void fft_dim(float* re, float* im,
                                        const float* twc, const float* tws,
                                        int tid, int cols)
{
  for (int idx = tid; idx < 16384; idx += NT_FFT) {
    int f = idx & 127, g = idx >> 7;
    int r = cols ? f : g;
    int i = cols ? g : f;
    int j = (int)(__brev((unsigned)i) >> 25);
    if (i < j) {
      int e0 = cols ? (i * 128 + r) : (r * 128 + i);
      int e1 = cols ? (j * 128 + r) : (r * 128 + j);
      float t0 = re[e0]; re[e0] = re[e1]; re[e1] = t0;
      float t1 = im[e0]; im[e0] = im[e1]; im[e1] = t1;
    }
  }
  __syncthreads();
  for (int s = 0; s < 7; ++s) {
    int half = 1 << s;
    for (int idx = tid; idx < 8192; idx += NT_FFT) {
      int t, r;
      if (cols) { r = idx & 127; t = idx >> 7; }
      else      { r = idx >> 6;  t = idx & 63; }
      int pos = t & (half - 1);
      int i0 = ((t >> s) << (s + 1)) + pos;
      int i1 = i0 + half;
      int e0 = cols ? (i0 * 128 + r) : (r * 128 + i0);
      int e1 = cols ? (i1 * 128 + r) : (r * 128 + i1);
      int tj = pos << (6 - s);
      float cs = twc[tj], sn = tws[tj];
      float br = re[e1], bi = im[e1];
      float tr = br * cs - bi * sn;
      float ti = br * sn + bi * cs;
      float ar = re[e0], ai = im[e0];
      re[e0] = ar + tr; im[e0] = ai + ti;
      re[e1] = ar - tr; im[e1] = ai - ti;
    }
    __syncthreads();
  }
}

__global__ __launch_bounds__(NT_FFT) void fft_amp_kernel(
    const float* __restrict__ x, const float* __restrict__ xref,
    const float* __restrict__ amp, float* __restrict__ feat)
{
  __shared__ float sre[16384];
  __shared__ float sim[16384];
  __shared__ float twc[64];
  __shared__ float tws[64];
  int tid = threadIdx.x;
  int blk = blockIdx.x;          // 0..255
  int tensor = blk >> 7;         // 0 = x, 1 = x_ref
  int plane = blk & 127;         // b*64 + c
  const float* src = (tensor ? xref : x) + (size_t)plane * HW;
  if (tid < 64) {
    float ang = -6.283185307179586f * (float)tid / 128.f;
    float sn, cs;
    __sincosf(ang, &sn, &cs);
    twc[tid] = cs; tws[tid] = sn;
  }
  for (int i = tid; i < 16384; i += NT_FFT) { sre[i] = src[i]; sim[i] = 0.f; }
  __syncthreads();
  fft_dim(sre, sim, twc, tws, tid, 0);
  fft_dim(sre, sim, twc, tws, tid, 1);
  const float* ampb = amp + (size_t)plane * (128 * 65);
  for (int idx = tid; idx < 16384; idx += NT_FFT) {
    int ky = idx >> 7, kx = idx & 127;
    float A = (kx <= 64) ? ampb[ky * 65 + kx]
                         : ampb[((128 - ky) & 127) * 65 + (128 - kx)];
    float th = atan2f(sim[idx], sre[idx]);
    float sn, cs;
    __sincosf(th, &sn, &cs);
    sre[idx] = A * cs;
    sim[idx] = -A * sn;   // conj
  }
  __syncthreads();
  fft_dim(sre, sim, twc, tws, tid, 0);
  fft_dim(sre, sim, twc, tws, tid, 1);
  int b = plane >> 6, c = plane & 63;
  float* dst = feat + ((size_t)b * 128 + tensor * 64 + c) * HW;
  for (int i = tid; i < 16384; i += NT_FFT) dst[i] = sre[i] * (1.f / 16384.f);
}

// ---------------------------------------------------------------------------
// 3x3 conv, pad=1, H=W=128. 8 output channels/block, 2 rows/thread.
// ---------------------------------------------------------------------------
#define COG 8
__global__ __launch_bounds__(256) void conv3x3_v2(
    const float* __restrict__ in1, const float* __restrict__ in2, int csplit,
    const float* __restrict__ w, const float* __restrict__ bias,
    float* __restrict__ out, int Cin, int Cout, int cogroups, int lrelu)
{
  __shared__ float tile[2][6][136];
  int blk = blockIdx.x;
  int ystrip = blk & 31;
  int t2 = blk >> 5;
  int cog = t2 % cogroups;
  int b = t2 / cogroups;
  int cobase = cog * COG;
  int tid = threadIdx.x;
  int col = tid & 127;
  int rg = tid >> 7;
  int y0 = ystrip << 2;

  if (tid < 12) {
    int row = tid >> 1, side = tid & 1;
    tile[0][row][side ? 132 : 3] = 0.f;
    tile[1][row][side ? 132 : 3] = 0.f;
  }

  float acc[COG][2];
  #pragma unroll
  for (int g = 0; g < COG; ++g) { acc[g][0] = 0.f; acc[g][1] = 0.f; }

  {
    const float* src = (0 < csplit) ? in1 + ((size_t)b * csplit) * HW : in2;
    if (tid < 192) {
      int row = tid >> 5, c4 = (tid & 31) << 2;
      int y = y0 - 1 + row;
      float4 v = make_float4(0.f, 0.f, 0.f, 0.f);
      if ((unsigned)y < 128u)
        v = *reinterpret_cast<const float4*>(src + y * Wd + c4);
      *reinterpret_cast<float4*>(&tile[0][row][4 + c4]) = v;
    }
  }

  for (int ci = 0; ci < Cin; ++ci) {
    float wv[COG][9];
    #pragma unroll
    for (int g = 0; g < COG; ++g) {
      int co = cobase + g;
      int cc = co < Cout ? co : Cout - 1;
      const float* wp = w + ((size_t)cc * Cin + ci) * 9;
      #pragma unroll
      for (int t = 0; t < 9; ++t) wv[g][t] = wp[t];
    }
    __syncthreads();
    if (ci + 1 < Cin) {
      int cn = ci + 1;
      const float* src = (cn < csplit)
          ? in1 + ((size_t)b * csplit + cn) * HW
          : in2 + ((size_t)b * (Cin - csplit) + (cn - csplit)) * HW;
      if (tid < 192) {
        int row = tid >> 5, c4 = (tid & 31) << 2;
        int y = y0 - 1 + row;
        float4 v = make_float4(0.f, 0.f, 0.f, 0.f);
        if ((unsigned)y < 128u)
          v = *reinterpret_cast<const float4*>(src + y * Wd + c4);
        *reinterpret_cast<float4*>(&tile[(ci + 1) & 1][row][4 + c4]) = v;
      }
    }
    const float (*tb)[136] = tile[ci & 1];
    float tv[4][3];
    int tr = rg << 1;
    #pragma unroll
    for (int rr = 0; rr < 4; ++rr) {
      #pragma unroll
      for (int vv = 0; vv < 3; ++vv)
        tv[rr][vv] = tb[tr + rr][col + 3 + vv];
    }
    #pragma unroll
    for (int g = 0; g < COG; ++g) {
      #pragma unroll
      for (int j = 0; j < 2; ++j) {
        float s = 0.f;
        #pragma unroll
        for (int u = 0; u < 3; ++u) {
          #pragma unroll
          for (int vv = 0; vv < 3; ++vv)
            s += tv[j + u][vv] * wv[g][u * 3 + vv];
        }
        acc[g][j] += s;
      }
    }
  }

  #pragma unroll
  for (int g = 0; g < COG; ++g) {
    int co = cobase + g;
    if (co < Cout) {
      float bv = bias[co];
      size_t ob = ((size_t)b * Cout + co) * HW;
      #pragma unroll
      for (int j = 0; j < 2; ++j) {
        int y = y0 + (rg << 1) + j;
        float v = acc[g][j] + bv;
        if (lrelu) v = v >= 0.f ? v : 0.1f * v;
        out[ob + (size_t)y * Wd + col] = v;
      }
    }
  }
}

// ---------------------------------------------------------------------------
// Transpose x[b][c][pix] -> xT[b][pix][c] (64x64 LDS tiles).
// ---------------------------------------------------------------------------
__global__ __launch_bounds__(256) void transpose_x(
    const float* __restrict__ x, float* __restrict__ xT)
{
  __shared__ float t[64][65];
  int blk = blockIdx.x;
  int b = blk >> 8;
  int pb = (blk & 255) << 6;
  int tid = threadIdx.x;
  int l = tid & 63;
  int g = tid >> 6;
  for (int it = 0; it < 16; ++it) {
    int c = g + it * 4;
    t[l][c] = x[((size_t)b * 64 + c) * HW + pb + l];
  }
  __syncthreads();
  for (int it = 0; it < 16; ++it) {
    int p = g + it * 4;
    xT[((size_t)b * HW + pb + p) * 64 + l] = t[p][l];
  }
}

// ---------------------------------------------------------------------------
// Weight prep: wdT[k][ci][co] from w_dcn[co][ci][k]; w1T[co][co2] from
// w_1x1[co2][co].
// ---------------------------------------------------------------------------
__global__ __launch_bounds__(256) void prep_w(
    const float* __restrict__ wd, const float* __restrict__ w1,
    float* __restrict__ wdT, float* __restrict__ w1T)
{
  int i = blockIdx.x * 256 + threadIdx.x;
  if (i < 36864) {
    int k = i >> 12, ci = (i >> 6) & 63, co = i & 63;
    wdT[i] = wd[co * 576 + ci * 9 + k];
  } else if (i < 40960) {
    int j = i - 36864;
    int co = j >> 6, co2 = j & 63;
    w1T[j] = w1[co2 * 64 + co];
  }
}

// ---------------------------------------------------------------------------
// Deformable conv + fused 1x1, register-tiled GEMM.
// Block: (b, 16 pixels of one row). Phases:
//   0: per-(k,p) offsets/mask  1: bilinear sampling (coalesced xT) -> S LDS
//   2: GEMM d = S*W (per-k LDS weight panel, 4px x 8co reg tiles, 8 ci-splits)
//   3: ci-split reduction + bias + lrelu -> Sd   4: 1x1 conv + lrelu -> out
// ---------------------------------------------------------------------------
__global__ __launch_bounds__(256) void deform_v2(
    const float* __restrict__ xT, const float* __restrict__ om,
    const float* __restrict__ wdT, const float* __restrict__ bd,
    const float* __restrict__ w1T, const float* __restrict__ b1,
    float* __restrict__ out)
{
  __shared__ float SM[9344];    // S[16][580]; later red[32][257] + Sd@8240
  __shared__ float wkf[4096];   // per-k weight panel [ci][co] xor-4 swizzled
  __shared__ int   gy0[144];
  __shared__ int   gx0[144];
  __shared__ float gwy[144];
  __shared__ float gwx[144];
  __shared__ float gm[144];

  int blk = blockIdx.x;
  int b = blk >> 10;
  int pb = (blk & 1023) << 4;
  int y = pb >> 7;
  int xb = pb & 127;
  int tid = threadIdx.x;

  // phase 0: offsets / mask
  if (tid < 144) {
    int k = tid >> 4, p = tid & 15;
    int xx = xb + p;
    const float* omb = om + (size_t)b * 27 * HW + (size_t)y * Wd + xx;
    float dy = omb[(2 * k) * HW];
    float dx = omb[(2 * k + 1) * HW];
    float mv = omb[(18 + k) * HW];
    mv = 1.f / (1.f + __expf(-mv));
    float py = (float)(y + (k / 3) - 1) + dy;
    float px = (float)(xx + (k % 3) - 1) + dx;
    float fy = floorf(py), fx = floorf(px);
    gy0[tid] = (int)fy; gx0[tid] = (int)fx;
    gwy[tid] = py - fy; gwx[tid] = px - fx;
    gm[tid] = mv;
  }
  __syncthreads();

  // phase 1: sampling (lanes = 64 channels -> coalesced 256B lines)
  {
    int c = tid & 63, q = tid >> 6;
    const float* xbp = xT + ((size_t)b * HW) * 64 + c;
    for (int k = 0; k < 9; ++k) {
      #pragma unroll
      for (int i = 0; i < 4; ++i) {
        int p = q * 4 + i;
        int gi = k * 16 + p;
        int yy = gy0[gi], xc = gx0[gi];
        float wy = gwy[gi], wx = gwx[gi];
        bool y0v = (unsigned)yy < 128u, y1v = (unsigned)(yy + 1) < 128u;
        bool x0v = (unsigned)xc < 128u, x1v = (unsigned)(xc + 1) < 128u;
        long off = ((long)yy * Wd + xc) * 64;
        float v00 = (y0v && x0v) ? xbp[off] : 0.f;
        float v01 = (y0v && x1v) ? xbp[off + 64] : 0.f;
        float v10 = (y1v && x0v) ? xbp[off + Wd * 64] : 0.f;
        float v11 = (y1v && x1v) ? xbp[off + Wd * 64 + 64] : 0.f;
        float vs = (v00 * (1.f - wx) + v01 * wx) * (1.f - wy)
                 + (v10 * (1.f - wx) + v11 * wx) * wy;
        SM[p * 580 + k * 64 + c] = vs * gm[gi];
      }
    }
  }
  __syncthreads();

  // phase 2: GEMM. thread tile: 4px (pg) x 8co (cg); 8-way ci split (r)
  int pg = tid & 3;
  int cg = (tid >> 2) & 7;
  int r = tid >> 5;
  int swz = (r & 1) << 2;
  float acc[4][8];
  #pragma unroll
  for (int i = 0; i < 4; ++i)
    #pragma unroll
    for (int j = 0; j < 8; ++j) acc[i][j] = 0.f;

  for (int k = 0; k < 9; ++k) {
    __syncthreads();   // protect previous panel reads
    #pragma unroll
    for (int t = 0; t < 4; ++t) {
      int fi = (tid + t * 256) * 4;
      int ci = fi >> 6, col = fi & 63;
      int sw = ((ci >> 3) & 1) << 2;
      float4 v = *reinterpret_cast<const float4*>(wdT + k * 4096 + fi);
      *reinterpret_cast<float4*>(&wkf[ci * 64 + (col ^ sw)]) = v;
    }
    __syncthreads();
    #pragma unroll
    for (int q4 = 0; q4 < 2; ++q4) {
      int cib = r * 8 + q4 * 4;
      float svf[4][4];
      #pragma unroll
      for (int i = 0; i < 4; ++i) {
        float4 t4 = *reinterpret_cast<const float4*>(
            &SM[(pg * 4 + i) * 580 + k * 64 + cib]);
        svf[i][0] = t4.x; svf[i][1] = t4.y; svf[i][2] = t4.z; svf[i][3] = t4.w;
      }
      float wlof[4][4], whif[4][4];
      #pragma unroll
      for (int jj = 0; jj < 4; ++jj) {
        const float* wrow = &wkf[(cib + jj) * 64];
        float4 a = *reinterpret_cast<const float4*>(&wrow[(cg * 8) ^ swz]);
        float4 c4 = *reinterpret_cast<const float4*>(&wrow[(cg * 8 + 4) ^ swz]);
        wlof[jj][0] = a.x; wlof[jj][1] = a.y; wlof[jj][2] = a.z; wlof[jj][3] = a.w;
        whif[jj][0] = c4.x; whif[jj][1] = c4.y; whif[jj][2] = c4.z; whif[jj][3] = c4.w;
      }
      #pragma unroll
      for (int i = 0; i < 4; ++i) {
        #pragma unroll
        for (int jj = 0; jj < 4; ++jj) {
          float s = svf[i][jj];
          #pragma unroll
          for (int j = 0; j < 4; ++j) {
            acc[i][j]     += s * wlof[jj][j];
            acc[i][j + 4] += s * whif[jj][j];
          }
        }
      }
    }
  }
  __syncthreads();

  // phase 3a: write partials to red[T][257] (aliases S region, S is dead)
  {
    int T = cg * 4 + pg;
    float* rb = &SM[T * 257 + r * 32];
    #pragma unroll
    for (int i = 0; i < 4; ++i)
      #pragma unroll
      for (int j = 0; j < 8; ++j)
        rb[i * 8 + j] = acc[i][j];
  }
  __syncthreads();

  // phase 3b: reduce 8 splits, bias + lrelu, store d into Sd (offset 8240)
  int p = tid & 15, cg2 = tid >> 4;
  {
    int T = (cg2 >> 1) * 4 + (p >> 2);
    int ebase = (p & 3) * 8 + (cg2 & 1) * 4;
    #pragma unroll
    for (int j = 0; j < 4; ++j) {
      float s = 0.f;
      #pragma unroll
      for (int rr = 0; rr < 8; ++rr)
        s += SM[T * 257 + rr * 32 + ebase + j];
      s += bd[cg2 * 4 + j];
      s = s >= 0.f ? s : 0.1f * s;
      SM[8240 + p * 65 + cg2 * 4 + j] = s;
    }
  }
  __syncthreads();

  // phase 4: fused 1x1 conv + lrelu -> out
  {
    float a0 = b1[cg2 * 4], a1 = b1[cg2 * 4 + 1];
    float a2 = b1[cg2 * 4 + 2], a3 = b1[cg2 * 4 + 3];
    const float* wp = w1T + cg2 * 4;
    const float* sd = &SM[8240 + p * 65];
    #pragma unroll 8
    for (int co = 0; co < 64; ++co) {
      float dv = sd[co];
      float4 wv = *reinterpret_cast<const float4*>(wp + co * 64);
      a0 += dv * wv.x; a1 += dv * wv.y; a2 += dv * wv.z; a3 += dv * wv.w;
    }
    float* ob = out + ((size_t)b * 64 + cg2 * 4) * HW + pb + p;
    float rv[4] = {a0, a1, a2, a3};
    #pragma unroll
    for (int j = 0; j < 4; ++j) {
      float v = rv[j];
      ob[(size_t)j * HW] = v >= 0.f ? v : 0.1f * v;
    }
  }
}

// ---------------------------------------------------------------------------
extern "C" void kernel_launch(void* const* d_in, const int* in_sizes, int n_in,
                              void* d_out, int out_size, void* d_ws, size_t ws_size,
                              hipStream_t stream) {
  (void)in_sizes; (void)n_in; (void)out_size; (void)ws_size;
  const float* x       = (const float*)d_in[0];
  const float* x_ref   = (const float*)d_in[1];
  const float* amp     = (const float*)d_in[2];
  const float* new_inp = (const float*)d_in[3];
  const float* w_off1  = (const float*)d_in[4];
  const float* b_off1  = (const float*)d_in[5];
  const float* w_off2  = (const float*)d_in[6];
  const float* b_off2  = (const float*)d_in[7];
  const float* w_om    = (const float*)d_in[8];
  const float* b_om    = (const float*)d_in[9];
  const float* w_dcn   = (const float*)d_in[10];
  const float* b_dcn   = (const float*)d_in[11];
  const float* w_1x1   = (const float*)d_in[12];
  const float* b_1x1   = (const float*)d_in[13];
  const float* w_3x3   = (const float*)d_in[14];
  const float* b_3x3   = (const float*)d_in[15];
  float* out = (float*)d_out;

  float* ws    = (float*)d_ws;
  float* feat  = ws;                    // B*128*HW = 4,194,304 f
  float* buf1  = feat + 4194304;        // B*64*HW  = 2,097,152 f
  float* buf2  = buf1 + 2097152;        // B*64*HW
  float* ombuf = buf2 + 2097152;        // B*27*HW
  // aliases into feat (dead after conv1):
  float* xT    = feat;                  // B*HW*64 = 2,097,152 f
  float* wdT   = feat + 2097152;        // 36,864 f
  float* w1T   = wdT + 36864;           // 4,096 f

  // 1) FFT amplitude swap -> feat
  hipLaunchKernelGGL(fft_amp_kernel, dim3(256), dim3(NT_FFT), 0, stream,
                     x, x_ref, amp, feat);
  // 2) conv1 (128->64) + lrelu
  hipLaunchKernelGGL(conv3x3_v2, dim3(512), dim3(256), 0, stream,
                     feat, (const float*)nullptr, 128, w_off1, b_off1, buf1,
                     128, 64, 8, 1);
  // 3) transposes/prep into now-dead feat region
  hipLaunchKernelGGL(transpose_x, dim3(512), dim3(256), 0, stream, x, xT);
  hipLaunchKernelGGL(prep_w, dim3(160), dim3(256), 0, stream,
                     w_dcn, w_1x1, wdT, w1T);
  // 4) conv2 (64->64) + lrelu
  hipLaunchKernelGGL(conv3x3_v2, dim3(512), dim3(256), 0, stream,
                     buf1, (const float*)nullptr, 64, w_off2, b_off2, buf2,
                     64, 64, 8, 1);
  // 5) om conv (64->27)
  hipLaunchKernelGGL(conv3x3_v2, dim3(256), dim3(256), 0, stream,
                     buf2, (const float*)nullptr, 64, w_om, b_om, ombuf,
                     64, 27, 4, 0);
  // 6) deform + fused 1x1 -> buf1
  hipLaunchKernelGGL(deform_v2, dim3(2048), dim3(256), 0, stream,
                     xT, ombuf, wdT, b_dcn, w1T, b_1x1, buf1);
  // 7) final 3x3 conv on concat([d2, new_inp]) -> out
  hipLaunchKernelGGL(conv3x3_v2, dim3(512), dim3(256), 0, stream,
                     buf1, new_inp, 64, w_3x3, b_3x3, out, 128, 64, 8, 0);
}

// Round 5
// 587.532 us; speedup vs baseline: 2.4651x; 1.3023x over previous
//
#include <hip/hip_runtime.h>
#include <hip/hip_bf16.h>
#include <math.h>

#define HW 16384
#define Wd 128
#define NT_FFT 1024

// ---------------------------------------------------------------------------
// FFT amplitude-replacement kernel: one block per (tensor, b, c) plane.
// ---------------------------------------------------------------------------
__device__ __forceinline__ void fft_dim(float* re, float* im,
                                        const float* twc, const float* tws,
                                        int tid, int cols)
{
  for (int idx = tid; idx < 16384; idx += NT_FFT) {
    int f = idx & 127, g = idx >> 7;
    int r = cols ? f : g;
    int i = cols ? g : f;
    int j = (int)(__brev((unsigned)i) >> 25);
    if (i < j) {
      int e0 = cols ? (i * 128 + r) : (r * 128 + i);
      int e1 = cols ? (j * 128 + r) : (r * 128 + j);
      float t0 = re[e0]; re[e0] = re[e1]; re[e1] = t0;
      float t1 = im[e0]; im[e0] = im[e1]; im[e1] = t1;
    }
  }
  __syncthreads();
  for (int s = 0; s < 7; ++s) {
    int half = 1 << s;
    for (int idx = tid; idx < 8192; idx += NT_FFT) {
      int t, r;
      if (cols) { r = idx & 127; t = idx >> 7; }
      else      { r = idx >> 6;  t = idx & 63; }
      int pos = t & (half - 1);
      int i0 = ((t >> s) << (s + 1)) + pos;
      int i1 = i0 + half;
      int e0 = cols ? (i0 * 128 + r) : (r * 128 + i0);
      int e1 = cols ? (i1 * 128 + r) : (r * 128 + i1);
      int tj = pos << (6 - s);
      float cs = twc[tj], sn = tws[tj];
      float br = re[e1], bi = im[e1];
      float tr = br * cs - bi * sn;
      float ti = br * sn + bi * cs;
      float ar = re[e0], ai = im[e0];
      re[e0] = ar + tr; im[e0] = ai + ti;
      re[e1] = ar - tr; im[e1] = ai - ti;
    }
    __syncthreads();
  }
}

__global__ __launch_bounds__(NT_FFT) void fft_amp_kernel(
    const float* __restrict__ x, const float* __restrict__ xref,
    const float* __restrict__ amp, float* __restrict__ feat)
{
  __shared__ float sre[16384];
  __shared__ float sim[16384];
  __shared__ float twc[64];
  __shared__ float tws[64];
  int tid = threadIdx.x;
  int blk = blockIdx.x;          // 0..255
  int tensor = blk >> 7;         // 0 = x, 1 = x_ref
  int plane = blk & 127;         // b*64 + c
  const float* src = (tensor ? xref : x) + (size_t)plane * HW;
  if (tid < 64) {
    float ang = -6.283185307179586f * (float)tid / 128.f;
    float sn, cs;
    __sincosf(ang, &sn, &cs);
    twc[tid] = cs; tws[tid] = sn;
  }
  for (int i = tid; i < 16384; i += NT_FFT) { sre[i] = src[i]; sim[i] = 0.f; }
  __syncthreads();
  fft_dim(sre, sim, twc, tws, tid, 0);
  fft_dim(sre, sim, twc, tws, tid, 1);
  const float* ampb = amp + (size_t)plane * (128 * 65);
  for (int idx = tid; idx < 16384; idx += NT_FFT) {
    int ky = idx >> 7, kx = idx & 127;
    float A = (kx <= 64) ? ampb[ky * 65 + kx]
                         : ampb[((128 - ky) & 127) * 65 + (128 - kx)];
    float th = atan2f(sim[idx], sre[idx]);
    float sn, cs;
    __sincosf(th, &sn, &cs);
    sre[idx] = A * cs;
    sim[idx] = -A * sn;   // conj
  }
  __syncthreads();
  fft_dim(sre, sim, twc, tws, tid, 0);
  fft_dim(sre, sim, twc, tws, tid, 1);
  int b = plane >> 6, c = plane & 63;
  float* dst = feat + ((size_t)b * 128 + tensor * 64 + c) * HW;
  for (int i = tid; i < 16384; i += NT_FFT) dst[i] = sre[i] * (1.f / 16384.f);
}

// ---------------------------------------------------------------------------
// 3x3 conv v3, pad=1, H=W=128. 8 co/block, 2-row strips (grid = B*cog*64 ->
// 4 blocks/CU), transposed weights wt[ci][co][k] -> one contiguous 72-dword
// scalar load per iteration. 256 threads = 128 cols x 2 rows.
// ---------------------------------------------------------------------------
__global__ __launch_bounds__(256) void conv3x3_v3(
    const float* __restrict__ in1, const float* __restrict__ in2, int csplit,
    const float* __restrict__ wt, const float* __restrict__ bias,
    float* __restrict__ out, int Cin, int Cout, int cogroups, int lrelu)
{
  __shared__ float tile[2][4][136];   // rows y0-1..y0+2; col 3=left halo,
                                      // 4..131 interior, 132=right halo
  int blk = blockIdx.x;
  int ystrip = blk & 63;
  int t2 = blk >> 6;
  int cog = t2 % cogroups;
  int b = t2 / cogroups;
  int cobase = cog << 3;
  int tid = threadIdx.x;
  int col = tid & 127;
  int rg = tid >> 7;                  // 0..1 -> output row y0+rg
  int y0 = ystrip << 1;

  if (tid < 16) {
    int buf = tid >> 3, row = (tid >> 1) & 3, side = tid & 1;
    tile[buf][row][side ? 132 : 3] = 0.f;
  }

  float acc[8];
  #pragma unroll
  for (int g = 0; g < 8; ++g) acc[g] = 0.f;

  // stage ci=0 into buffer 0
  {
    const float* src = (0 < csplit) ? in1 + ((size_t)b * csplit) * HW : in2;
    if (tid < 128) {
      int row = tid >> 5, c4 = (tid & 31) << 2;
      int y = y0 - 1 + row;
      float4 v = make_float4(0.f, 0.f, 0.f, 0.f);
      if ((unsigned)y < 128u)
        v = *reinterpret_cast<const float4*>(src + y * Wd + c4);
      *reinterpret_cast<float4*>(&tile[0][row][4 + c4]) = v;
    }
  }

  for (int ci = 0; ci < Cin; ++ci) {
    // contiguous 72-dword uniform weight load (SGPRs)
    const float* wp = wt + ((size_t)ci * Cout + cobase) * 9;
    float wv[8][9];
    #pragma unroll
    for (int g = 0; g < 8; ++g)
      #pragma unroll
      for (int t = 0; t < 9; ++t) wv[g][t] = wp[g * 9 + t];

    __syncthreads();
    if (ci + 1 < Cin) {
      int cn = ci + 1;
      const float* src = (cn < csplit)
          ? in1 + ((size_t)b * csplit + cn) * HW
          : in2 + ((size_t)b * (Cin - csplit) + (cn - csplit)) * HW;
      if (tid < 128) {
        int row = tid >> 5, c4 = (tid & 31) << 2;
        int y = y0 - 1 + row;
        float4 v = make_float4(0.f, 0.f, 0.f, 0.f);
        if ((unsigned)y < 128u)
          v = *reinterpret_cast<const float4*>(src + y * Wd + c4);
        *reinterpret_cast<float4*>(&tile[cn & 1][row][4 + c4]) = v;
      }
    }
    const float (*tb)[136] = tile[ci & 1];
    float tv[3][3];
    #pragma unroll
    for (int u = 0; u < 3; ++u)
      #pragma unroll
      for (int vv = 0; vv < 3; ++vv)
        tv[u][vv] = tb[rg + u][col + 3 + vv];
    #pragma unroll
    for (int g = 0; g < 8; ++g) {
      float s = 0.f;
      #pragma unroll
      for (int u = 0; u < 3; ++u)
        #pragma unroll
        for (int vv = 0; vv < 3; ++vv)
          s += tv[u][vv] * wv[g][u * 3 + vv];
      acc[g] += s;
    }
  }

  #pragma unroll
  for (int g = 0; g < 8; ++g) {
    int co = cobase + g;
    if (co < Cout) {
      float v = acc[g] + bias[co];
      if (lrelu) v = v >= 0.f ? v : 0.1f * v;
      out[((size_t)b * Cout + co) * HW + (size_t)(y0 + rg) * Wd + col] = v;
    }
  }
}

// ---------------------------------------------------------------------------
// Transpose x[b][c][pix] -> xT[b][pix][c] (64x64 LDS tiles).
// ---------------------------------------------------------------------------
__global__ __launch_bounds__(256) void transpose_x(
    const float* __restrict__ x, float* __restrict__ xT)
{
  __shared__ float t[64][65];
  int blk = blockIdx.x;
  int b = blk >> 8;
  int pb = (blk & 255) << 6;
  int tid = threadIdx.x;
  int l = tid & 63;
  int g = tid >> 6;
  for (int it = 0; it < 16; ++it) {
    int c = g + it * 4;
    t[l][c] = x[((size_t)b * 64 + c) * HW + pb + l];
  }
  __syncthreads();
  for (int it = 0; it < 16; ++it) {
    int p = g + it * 4;
    xT[((size_t)b * HW + pb + p) * 64 + l] = t[p][l];
  }
}

// ---------------------------------------------------------------------------
// All weight prep: wdT[k][ci][co], w1T[co][co2], and the four transposed
// conv weights wt[ci][co][k].
// ---------------------------------------------------------------------------
__global__ __launch_bounds__(256) void prep_all(
    const float* __restrict__ wd, const float* __restrict__ w1,
    const float* __restrict__ w_off1, const float* __restrict__ w_off2,
    const float* __restrict__ w_om, const float* __restrict__ w_3x3,
    float* __restrict__ wdT, float* __restrict__ w1T,
    float* __restrict__ wt1, float* __restrict__ wt2,
    float* __restrict__ wtm, float* __restrict__ wt3)
{
  int i = blockIdx.x * 256 + threadIdx.x;
  if (i < 36864) {                    // wdT[k][ci][co]
    int k = i >> 12, ci = (i >> 6) & 63, co = i & 63;
    wdT[i] = wd[co * 576 + ci * 9 + k];
  } else if (i < 40960) {             // w1T[co][co2]
    int j = i - 36864;
    w1T[j] = w1[(j & 63) * 64 + (j >> 6)];
  } else if (i < 114688) {            // wt1: [128][64][9] from [64][128][9]
    int j = i - 40960;
    int k = j % 9, t = j / 9, co = t & 63, ci = t >> 6;
    wt1[j] = w_off1[((size_t)co * 128 + ci) * 9 + k];
  } else if (i < 151552) {            // wt2: [64][64][9] from [64][64][9]
    int j = i - 114688;
    int k = j % 9, t = j / 9, co = t & 63, ci = t >> 6;
    wt2[j] = w_off2[((size_t)co * 64 + ci) * 9 + k];
  } else if (i < 167168) {            // wtm: [64][27][9]+pad from [27][64][9]
    int j = i - 151552;
    if (j < 15552) {
      int k = j % 9, t = j / 9, co = t % 27, ci = t / 27;
      wtm[j] = w_om[((size_t)co * 64 + ci) * 9 + k];
    } else wtm[j] = 0.f;
  } else if (i < 240896) {            // wt3: [128][64][9] from [64][128][9]
    int j = i - 167168;
    int k = j % 9, t = j / 9, co = t & 63, ci = t >> 6;
    wt3[j] = w_3x3[((size_t)co * 128 + ci) * 9 + k];
  }
}

// ---------------------------------------------------------------------------
// Deformable conv + fused 1x1, register-tiled GEMM (unchanged from r2).
// ---------------------------------------------------------------------------
__global__ __launch_bounds__(256) void deform_v2(
    const float* __restrict__ xT, const float* __restrict__ om,
    const float* __restrict__ wdT, const float* __restrict__ bd,
    const float* __restrict__ w1T, const float* __restrict__ b1,
    float* __restrict__ out)
{
  __shared__ float SM[9344];    // S[16][580]; later red[32][257] + Sd@8240
  __shared__ float wkf[4096];   // per-k weight panel [ci][co] xor-4 swizzled
  __shared__ int   gy0[144];
  __shared__ int   gx0[144];
  __shared__ float gwy[144];
  __shared__ float gwx[144];
  __shared__ float gm[144];

  int blk = blockIdx.x;
  int b = blk >> 10;
  int pb = (blk & 1023) << 4;
  int y = pb >> 7;
  int xb = pb & 127;
  int tid = threadIdx.x;

  if (tid < 144) {
    int k = tid >> 4, p = tid & 15;
    int xx = xb + p;
    const float* omb = om + (size_t)b * 27 * HW + (size_t)y * Wd + xx;
    float dy = omb[(2 * k) * HW];
    float dx = omb[(2 * k + 1) * HW];
    float mv = omb[(18 + k) * HW];
    mv = 1.f / (1.f + __expf(-mv));
    float py = (float)(y + (k / 3) - 1) + dy;
    float px = (float)(xx + (k % 3) - 1) + dx;
    float fy = floorf(py), fx = floorf(px);
    gy0[tid] = (int)fy; gx0[tid] = (int)fx;
    gwy[tid] = py - fy; gwx[tid] = px - fx;
    gm[tid] = mv;
  }
  __syncthreads();

  {
    int c = tid & 63, q = tid >> 6;
    const float* xbp = xT + ((size_t)b * HW) * 64 + c;
    for (int k = 0; k < 9; ++k) {
      #pragma unroll
      for (int i = 0; i < 4; ++i) {
        int p = q * 4 + i;
        int gi = k * 16 + p;
        int yy = gy0[gi], xc = gx0[gi];
        float wy = gwy[gi], wx = gwx[gi];
        bool y0v = (unsigned)yy < 128u, y1v = (unsigned)(yy + 1) < 128u;
        bool x0v = (unsigned)xc < 128u, x1v = (unsigned)(xc + 1) < 128u;
        long off = ((long)yy * Wd + xc) * 64;
        float v00 = (y0v && x0v) ? xbp[off] : 0.f;
        float v01 = (y0v && x1v) ? xbp[off + 64] : 0.f;
        float v10 = (y1v && x0v) ? xbp[off + Wd * 64] : 0.f;
        float v11 = (y1v && x1v) ? xbp[off + Wd * 64 + 64] : 0.f;
        float vs = (v00 * (1.f - wx) + v01 * wx) * (1.f - wy)
                 + (v10 * (1.f - wx) + v11 * wx) * wy;
        SM[p * 580 + k * 64 + c] = vs * gm[gi];
      }
    }
  }
  __syncthreads();

  int pg = tid & 3;
  int cg = (tid >> 2) & 7;
  int r = tid >> 5;
  int swz = (r & 1) << 2;
  float acc[4][8];
  #pragma unroll
  for (int i = 0; i < 4; ++i)
    #pragma unroll
    for (int j = 0; j < 8; ++j) acc[i][j] = 0.f;

  for (int k = 0; k < 9; ++k) {
    __syncthreads();
    #pragma unroll
    for (int t = 0; t < 4; ++t) {
      int fi = (tid + t * 256) * 4;
      int ci = fi >> 6, col = fi & 63;
      int sw = ((ci >> 3) & 1) << 2;
      float4 v = *reinterpret_cast<const float4*>(wdT + k * 4096 + fi);
      *reinterpret_cast<float4*>(&wkf[ci * 64 + (col ^ sw)]) = v;
    }
    __syncthreads();
    #pragma unroll
    for (int q4 = 0; q4 < 2; ++q4) {
      int cib = r * 8 + q4 * 4;
      float svf[4][4];
      #pragma unroll
      for (int i = 0; i < 4; ++i) {
        float4 t4 = *reinterpret_cast<const float4*>(
            &SM[(pg * 4 + i) * 580 + k * 64 + cib]);
        svf[i][0] = t4.x; svf[i][1] = t4.y; svf[i][2] = t4.z; svf[i][3] = t4.w;
      }
      float wlof[4][4], whif[4][4];
      #pragma unroll
      for (int jj = 0; jj < 4; ++jj) {
        const float* wrow = &wkf[(cib + jj) * 64];
        float4 a = *reinterpret_cast<const float4*>(&wrow[(cg * 8) ^ swz]);
        float4 c4 = *reinterpret_cast<const float4*>(&wrow[(cg * 8 + 4) ^ swz]);
        wlof[jj][0] = a.x; wlof[jj][1] = a.y; wlof[jj][2] = a.z; wlof[jj][3] = a.w;
        whif[jj][0] = c4.x; whif[jj][1] = c4.y; whif[jj][2] = c4.z; whif[jj][3] = c4.w;
      }
      #pragma unroll
      for (int i = 0; i < 4; ++i) {
        #pragma unroll
        for (int jj = 0; jj < 4; ++jj) {
          float s = svf[i][jj];
          #pragma unroll
          for (int j = 0; j < 4; ++j) {
            acc[i][j]     += s * wlof[jj][j];
            acc[i][j + 4] += s * whif[jj][j];
          }
        }
      }
    }
  }
  __syncthreads();

  {
    int T = cg * 4 + pg;
    float* rb = &SM[T * 257 + r * 32];
    #pragma unroll
    for (int i = 0; i < 4; ++i)
      #pragma unroll
      for (int j = 0; j < 8; ++j)
        rb[i * 8 + j] = acc[i][j];
  }
  __syncthreads();

  int p = tid & 15, cg2 = tid >> 4;
  {
    int T = (cg2 >> 1) * 4 + (p >> 2);
    int ebase = (p & 3) * 8 + (cg2 & 1) * 4;
    #pragma unroll
    for (int j = 0; j < 4; ++j) {
      float s = 0.f;
      #pragma unroll
      for (int rr = 0; rr < 8; ++rr)
        s += SM[T * 257 + rr * 32 + ebase + j];
      s += bd[cg2 * 4 + j];
      s = s >= 0.f ? s : 0.1f * s;
      SM[8240 + p * 65 + cg2 * 4 + j] = s;
    }
  }
  __syncthreads();

  {
    float a0 = b1[cg2 * 4], a1 = b1[cg2 * 4 + 1];
    float a2 = b1[cg2 * 4 + 2], a3 = b1[cg2 * 4 + 3];
    const float* wp = w1T + cg2 * 4;
    const float* sd = &SM[8240 + p * 65];
    #pragma unroll 8
    for (int co = 0; co < 64; ++co) {
      float dv = sd[co];
      float4 wv = *reinterpret_cast<const float4*>(wp + co * 64);
      a0 += dv * wv.x; a1 += dv * wv.y; a2 += dv * wv.z; a3 += dv * wv.w;
    }
    float* ob = out + ((size_t)b * 64 + cg2 * 4) * HW + pb + p;
    float rv[4] = {a0, a1, a2, a3};
    #pragma unroll
    for (int j = 0; j < 4; ++j) {
      float v = rv[j];
      ob[(size_t)j * HW] = v >= 0.f ? v : 0.1f * v;
    }
  }
}

// ---------------------------------------------------------------------------
extern "C" void kernel_launch(void* const* d_in, const int* in_sizes, int n_in,
                              void* d_out, int out_size, void* d_ws, size_t ws_size,
                              hipStream_t stream) {
  (void)in_sizes; (void)n_in; (void)out_size; (void)ws_size;
  const float* x       = (const float*)d_in[0];
  const float* x_ref   = (const float*)d_in[1];
  const float* amp     = (const float*)d_in[2];
  const float* new_inp = (const float*)d_in[3];
  const float* w_off1  = (const float*)d_in[4];
  const float* b_off1  = (const float*)d_in[5];
  const float* w_off2  = (const float*)d_in[6];
  const float* b_off2  = (const float*)d_in[7];
  const float* w_om    = (const float*)d_in[8];
  const float* b_om    = (const float*)d_in[9];
  const float* w_dcn   = (const float*)d_in[10];
  const float* b_dcn   = (const float*)d_in[11];
  const float* w_1x1   = (const float*)d_in[12];
  const float* b_1x1   = (const float*)d_in[13];
  const float* w_3x3   = (const float*)d_in[14];
  const float* b_3x3   = (const float*)d_in[15];
  float* out = (float*)d_out;

  float* ws    = (float*)d_ws;
  float* feat  = ws;                    // B*128*HW = 4,194,304 f
  float* buf1  = feat + 4194304;        // B*64*HW  = 2,097,152 f
  float* buf2  = buf1 + 2097152;        // B*64*HW
  float* ombuf = buf2 + 2097152;        // B*27*HW  = 884,736 f
  float* wreg  = ombuf + 884736;        // weight region, 240,896 f
  float* wdT   = wreg;                  // 36,864
  float* w1T   = wdT + 36864;           // 4,096
  float* wt1   = w1T + 4096;            // 73,728
  float* wt2   = wt1 + 73728;           // 36,864
  float* wtm   = wt2 + 36864;           // 15,616
  float* wt3   = wtm + 15616;           // 73,728
  float* xT    = feat;                  // alias: feat dead after conv1

  // 0) weight prep (independent of everything else)
  hipLaunchKernelGGL(prep_all, dim3(941), dim3(256), 0, stream,
                     w_dcn, w_1x1, w_off1, w_off2, w_om, w_3x3,
                     wdT, w1T, wt1, wt2, wtm, wt3);
  // 1) FFT amplitude swap -> feat
  hipLaunchKernelGGL(fft_amp_kernel, dim3(256), dim3(NT_FFT), 0, stream,
                     x, x_ref, amp, feat);
  // 2) conv1 (128->64) + lrelu
  hipLaunchKernelGGL(conv3x3_v3, dim3(1024), dim3(256), 0, stream,
                     feat, (const float*)nullptr, 128, wt1, b_off1, buf1,
                     128, 64, 8, 1);
  // 3) x transpose into now-dead feat region
  hipLaunchKernelGGL(transpose_x, dim3(512), dim3(256), 0, stream, x, xT);
  // 4) conv2 (64->64) + lrelu
  hipLaunchKernelGGL(conv3x3_v3, dim3(1024), dim3(256), 0, stream,
                     buf1, (const float*)nullptr, 64, wt2, b_off2, buf2,
                     64, 64, 8, 1);
  // 5) om conv (64->27)
  hipLaunchKernelGGL(conv3x3_v3, dim3(512), dim3(256), 0, stream,
                     buf2, (const float*)nullptr, 64, wtm, b_om, ombuf,
                     64, 27, 4, 0);
  // 6) deform + fused 1x1 -> buf1
  hipLaunchKernelGGL(deform_v2, dim3(2048), dim3(256), 0, stream,
                     xT, ombuf, wdT, b_dcn, w1T, b_1x1, buf1);
  // 7) final 3x3 conv on concat([d2, new_inp]) -> out
  hipLaunchKernelGGL(conv3x3_v3, dim3(1024), dim3(256), 0, stream,
                     buf1, new_inp, 64, wt3, b_3x3, out, 128, 64, 8, 0);
}